// Round 3
// baseline (24001.791 us; speedup 1.0000x reference)
//
#include <hip/hip_runtime.h>
#include <math.h>

#define B_ 32
#define T_ 512
#define I_ 512
#define H_ 1024
#define O_ 512
#define MT (B_*T_)   // 16384 rows
#define NBLK 256     // persistent-kernel grid: 1 block per 4 H-columns

// ---------------------------------------------------------------------------
// GEMM: C[m][n] = bias[n] + sum_k A[m][k] * Bm[n][k]   (both row-major, "NT")
// BM=BN=128, BK=16, 256 threads, 8x8 microtile per thread.
// ---------------------------------------------------------------------------
__global__ __launch_bounds__(256)
void gemm_nt_bias(float* __restrict__ C, const float* __restrict__ A,
                  const float* __restrict__ Bm, const float* __restrict__ bias,
                  int M, int N, int K) {
  __shared__ float As[16][132];
  __shared__ float Bs[16][132];
  const int tid = threadIdx.x;
  const int bm = blockIdx.x * 128;
  const int bn = blockIdx.y * 128;
  const int lr = tid >> 2;
  const int lc = (tid & 3) * 4;
  const int tm = (tid >> 4) * 8;
  const int tn = (tid & 15) * 8;

  float acc[8][8];
#pragma unroll
  for (int i = 0; i < 8; ++i)
#pragma unroll
    for (int j = 0; j < 8; ++j) acc[i][j] = 0.f;

  for (int k0 = 0; k0 < K; k0 += 16) {
    float4 a0 = *(const float4*)(A  + (size_t)(bm + lr)      * K + k0 + lc);
    float4 a1 = *(const float4*)(A  + (size_t)(bm + lr + 64) * K + k0 + lc);
    float4 b0 = *(const float4*)(Bm + (size_t)(bn + lr)      * K + k0 + lc);
    float4 b1 = *(const float4*)(Bm + (size_t)(bn + lr + 64) * K + k0 + lc);
    __syncthreads();
    As[lc+0][lr]    = a0.x; As[lc+1][lr]    = a0.y; As[lc+2][lr]    = a0.z; As[lc+3][lr]    = a0.w;
    As[lc+0][lr+64] = a1.x; As[lc+1][lr+64] = a1.y; As[lc+2][lr+64] = a1.z; As[lc+3][lr+64] = a1.w;
    Bs[lc+0][lr]    = b0.x; Bs[lc+1][lr]    = b0.y; Bs[lc+2][lr]    = b0.z; Bs[lc+3][lr]    = b0.w;
    Bs[lc+0][lr+64] = b1.x; Bs[lc+1][lr+64] = b1.y; Bs[lc+2][lr+64] = b1.z; Bs[lc+3][lr+64] = b1.w;
    __syncthreads();
#pragma unroll
    for (int k = 0; k < 16; ++k) {
      float a[8], b[8];
      *(float4*)&a[0] = *(const float4*)&As[k][tm];
      *(float4*)&a[4] = *(const float4*)&As[k][tm + 4];
      *(float4*)&b[0] = *(const float4*)&Bs[k][tn];
      *(float4*)&b[4] = *(const float4*)&Bs[k][tn + 4];
#pragma unroll
      for (int i = 0; i < 8; ++i)
#pragma unroll
        for (int j = 0; j < 8; ++j) acc[i][j] += a[i] * b[j];
    }
  }

  float bv[8];
#pragma unroll
  for (int j = 0; j < 8; ++j) bv[j] = bias[bn + tn + j];
#pragma unroll
  for (int i = 0; i < 8; ++i) {
    float* crow = C + (size_t)(bm + tm + i) * N + bn + tn;
    float4 o0 = {acc[i][0]+bv[0], acc[i][1]+bv[1], acc[i][2]+bv[2], acc[i][3]+bv[3]};
    float4 o1 = {acc[i][4]+bv[4], acc[i][5]+bv[5], acc[i][6]+bv[6], acc[i][7]+bv[7]};
    *(float4*)(crow)     = o0;
    *(float4*)(crow + 4) = o1;
  }
}

// ---------------------------------------------------------------------------
// Persistent recurrence kernel: ONE launch for all T=512 steps.
// 256 blocks; block g owns output columns j0=4g..4g+3 for ALL 32 batches.
// W rows staged to LDS once. Per step: stage h_{t-1}, dot, tanh, write z,
// then device-scope barrier (atomic counter, monotone target).
// Co-residency: 256 blocks <= 256 CUs, ~38KB LDS / 4 waves per block ->
// every block is resident; no block waits on another's completion.
// ---------------------------------------------------------------------------
__global__ __launch_bounds__(256)
void rnn_persistent(float* __restrict__ z, const float* __restrict__ h0,
                    const float* __restrict__ Whh, const float* __restrict__ bhh,
                    unsigned int* __restrict__ ctr) {
  __shared__ float Ws[4][1032];      // 4 W_hh rows, resident for whole kernel
  __shared__ float hs[32][132];      // h tile: 32 b x 128 k (+pad)
  __shared__ float red[8 * 32 * 4];  // k-split partials

  const int tid = threadIdx.x;
  const int j0 = blockIdx.x * 4;

  // ---- stage W rows once ----
  {
    const int j  = tid >> 6;
    const int c4 = tid & 63;
    const float4* src = (const float4*)(Whh + (size_t)(j0 + j) * H_);
#pragma unroll
    for (int i = 0; i < 4; ++i) {
      float4 v = src[c4 + 64 * i];
      *(float4*)&Ws[j][(c4 + 64 * i) * 4] = v;
    }
  }

  const int b    = tid & 31;
  const int s    = tid >> 5;       // 0..7 k-split
  const int srow = tid >> 3;       // staging row 0..31
  const int sc4  = tid & 7;

  for (int t = 0; t < T_; ++t) {
    const float* hbase;
    size_t hstride;
    if (t == 0) { hbase = h0;                     hstride = H_; }
    else        { hbase = z + (size_t)(t-1) * H_; hstride = (size_t)T_ * H_; }

    float partial[4] = {0.f, 0.f, 0.f, 0.f};

    for (int kt = 0; kt < H_; kt += 128) {
      __syncthreads();
      const float* hsrc = hbase + (size_t)srow * hstride + kt;
#pragma unroll
      for (int i = 0; i < 4; ++i) {
        float4 v = *(const float4*)(hsrc + (sc4 + 8 * i) * 4);
        *(float4*)&hs[srow][(sc4 + 8 * i) * 4] = v;
      }
      __syncthreads();
#pragma unroll
      for (int m = 0; m < 4; ++m) {
        const int g  = m * 8 + s;
        float4 hv = *(const float4*)&hs[b][g * 4];
        const int kw = kt + g * 4;
#pragma unroll
        for (int j = 0; j < 4; ++j) {
          float4 wv = *(const float4*)&Ws[j][kw];
          partial[j] += hv.x*wv.x + hv.y*wv.y + hv.z*wv.z + hv.w*wv.w;
        }
      }
    }

    __syncthreads();
#pragma unroll
    for (int j = 0; j < 4; ++j) red[(s * 32 + b) * 4 + j] = partial[j];
    __syncthreads();

    if (tid < 128) {
      const int rb = tid >> 2;
      const int rj = tid & 3;
      float v = 0.f;
#pragma unroll
      for (int ss = 0; ss < 8; ++ss) v += red[(ss * 32 + rb) * 4 + rj];
      const size_t idx = (size_t)rb * T_ * H_ + (size_t)t * H_ + j0 + rj;
      v += z[idx] + bhh[j0 + rj];
      z[idx] = tanhf(v);
    }

    // ---- device-scope grid barrier for step t ----
    __threadfence();            // release: make z writes device-visible
    __syncthreads();            // all threads' stores+fences done
    if (tid == 0) {
      atomicAdd(ctr, 1u);       // device-scope by default
      const unsigned target = (unsigned)(t + 1) * NBLK;
      while (__hip_atomic_load(ctr, __ATOMIC_ACQUIRE, __HIP_MEMORY_SCOPE_AGENT) < target)
        __builtin_amdgcn_s_sleep(2);
    }
    __syncthreads();
    // acquire fence: invalidate L1 so peers' z writes (incl. lines this CU
    // cached pre-write when reading `pre`) are re-fetched fresh (G16).
    __builtin_amdgcn_fence(__ATOMIC_ACQUIRE, "agent");
  }
}

// ---------------------------------------------------------------------------
// Row softmax in place over O_=512 columns. One wave per row.
// ---------------------------------------------------------------------------
__global__ __launch_bounds__(256)
void softmax_rows(float* __restrict__ P) {
  const int row  = blockIdx.x * 4 + (threadIdx.x >> 6);
  const int lane = threadIdx.x & 63;
  float* p = P + (size_t)row * O_;
  float4 v0 = *(const float4*)(p + lane * 4);
  float4 v1 = *(const float4*)(p + 256 + lane * 4);

  float m = fmaxf(fmaxf(fmaxf(v0.x, v0.y), fmaxf(v0.z, v0.w)),
                  fmaxf(fmaxf(v1.x, v1.y), fmaxf(v1.z, v1.w)));
#pragma unroll
  for (int off = 32; off; off >>= 1) m = fmaxf(m, __shfl_xor(m, off, 64));

  v0.x = __expf(v0.x - m); v0.y = __expf(v0.y - m);
  v0.z = __expf(v0.z - m); v0.w = __expf(v0.w - m);
  v1.x = __expf(v1.x - m); v1.y = __expf(v1.y - m);
  v1.z = __expf(v1.z - m); v1.w = __expf(v1.w - m);

  float s = v0.x + v0.y + v0.z + v0.w + v1.x + v1.y + v1.z + v1.w;
#pragma unroll
  for (int off = 32; off; off >>= 1) s += __shfl_xor(s, off, 64);
  const float inv = 1.f / s;

  v0.x *= inv; v0.y *= inv; v0.z *= inv; v0.w *= inv;
  v1.x *= inv; v1.y *= inv; v1.z *= inv; v1.w *= inv;
  *(float4*)(p + lane * 4)       = v0;
  *(float4*)(p + 256 + lane * 4) = v1;
}

// ---------------------------------------------------------------------------
extern "C" void kernel_launch(void* const* d_in, const int* in_sizes, int n_in,
                              void* d_out, int out_size, void* d_ws, size_t ws_size,
                              hipStream_t stream) {
  const float* x    = (const float*)d_in[0];   // [B,T,I]
  const float* h0   = (const float*)d_in[1];   // [1,B,H]
  const float* Wih  = (const float*)d_in[2];   // [H,I]
  const float* Whh  = (const float*)d_in[3];   // [H,H]
  const float* bih  = (const float*)d_in[4];   // [H]
  const float* bhh  = (const float*)d_in[5];   // [H]
  const float* Wout = (const float*)d_in[6];   // [O,H]
  const float* bout = (const float*)d_in[7];   // [O]

  float* outp = (float*)d_out;                       // [B,T,O]
  float* z    = (float*)d_out + (size_t)MT * O_;     // [B,T,H]
  unsigned int* ctr = (unsigned int*)d_ws;           // barrier counter

  // zero the barrier counter (ws is poisoned 0xAA before every replay)
  (void)hipMemsetAsync(ctr, 0, 64, stream);

  // Phase 1: pre = x @ W_ih^T + b_ih, written directly into z region
  gemm_nt_bias<<<dim3(MT / 128, H_ / 128), 256, 0, stream>>>(z, x, Wih, bih, MT, H_, I_);

  // Phase 2: ONE persistent kernel for all 512 recurrence steps
  rnn_persistent<<<dim3(NBLK), 256, 0, stream>>>(z, h0, Whh, bhh, ctr);

  // Phase 3: logits = z @ W_out^T + b_out, then row softmax in place
  gemm_nt_bias<<<dim3(MT / 128, O_ / 128), 256, 0, stream>>>(outp, z, Wout, bout, MT, O_, H_);
  softmax_rows<<<dim3(MT / 4), 256, 0, stream>>>(outp);
}

// Round 4
// 9231.106 us; speedup vs baseline: 2.6001x; 2.6001x over previous
//
#include <hip/hip_runtime.h>
#include <math.h>

#define B_ 32
#define T_ 512
#define I_ 512
#define H_ 1024
#define O_ 512
#define MT (B_*T_)   // 16384 rows
#define NBLK 256     // persistent-kernel grid: 1 block per 4 H-columns

// ---------------------------------------------------------------------------
// GEMM: C[m][n] = bias[n] + sum_k A[m][k] * Bm[n][k]   (both row-major, "NT")
// BM=BN=128, BK=16, 256 threads, 8x8 microtile per thread.
// ---------------------------------------------------------------------------
__global__ __launch_bounds__(256)
void gemm_nt_bias(float* __restrict__ C, const float* __restrict__ A,
                  const float* __restrict__ Bm, const float* __restrict__ bias,
                  int M, int N, int K) {
  __shared__ float As[16][132];
  __shared__ float Bs[16][132];
  const int tid = threadIdx.x;
  const int bm = blockIdx.x * 128;
  const int bn = blockIdx.y * 128;
  const int lr = tid >> 2;
  const int lc = (tid & 3) * 4;
  const int tm = (tid >> 4) * 8;
  const int tn = (tid & 15) * 8;

  float acc[8][8];
#pragma unroll
  for (int i = 0; i < 8; ++i)
#pragma unroll
    for (int j = 0; j < 8; ++j) acc[i][j] = 0.f;

  for (int k0 = 0; k0 < K; k0 += 16) {
    float4 a0 = *(const float4*)(A  + (size_t)(bm + lr)      * K + k0 + lc);
    float4 a1 = *(const float4*)(A  + (size_t)(bm + lr + 64) * K + k0 + lc);
    float4 b0 = *(const float4*)(Bm + (size_t)(bn + lr)      * K + k0 + lc);
    float4 b1 = *(const float4*)(Bm + (size_t)(bn + lr + 64) * K + k0 + lc);
    __syncthreads();
    As[lc+0][lr]    = a0.x; As[lc+1][lr]    = a0.y; As[lc+2][lr]    = a0.z; As[lc+3][lr]    = a0.w;
    As[lc+0][lr+64] = a1.x; As[lc+1][lr+64] = a1.y; As[lc+2][lr+64] = a1.z; As[lc+3][lr+64] = a1.w;
    Bs[lc+0][lr]    = b0.x; Bs[lc+1][lr]    = b0.y; Bs[lc+2][lr]    = b0.z; Bs[lc+3][lr]    = b0.w;
    Bs[lc+0][lr+64] = b1.x; Bs[lc+1][lr+64] = b1.y; Bs[lc+2][lr+64] = b1.z; Bs[lc+3][lr+64] = b1.w;
    __syncthreads();
#pragma unroll
    for (int k = 0; k < 16; ++k) {
      float a[8], b[8];
      *(float4*)&a[0] = *(const float4*)&As[k][tm];
      *(float4*)&a[4] = *(const float4*)&As[k][tm + 4];
      *(float4*)&b[0] = *(const float4*)&Bs[k][tn];
      *(float4*)&b[4] = *(const float4*)&Bs[k][tn + 4];
#pragma unroll
      for (int i = 0; i < 8; ++i)
#pragma unroll
        for (int j = 0; j < 8; ++j) acc[i][j] += a[i] * b[j];
    }
  }

  float bv[8];
#pragma unroll
  for (int j = 0; j < 8; ++j) bv[j] = bias[bn + tn + j];
#pragma unroll
  for (int i = 0; i < 8; ++i) {
    float* crow = C + (size_t)(bm + tm + i) * N + bn + tn;
    float4 o0 = {acc[i][0]+bv[0], acc[i][1]+bv[1], acc[i][2]+bv[2], acc[i][3]+bv[3]};
    float4 o1 = {acc[i][4]+bv[4], acc[i][5]+bv[5], acc[i][6]+bv[6], acc[i][7]+bv[7]};
    *(float4*)(crow)     = o0;
    *(float4*)(crow + 4) = o1;
  }
}

// ---------------------------------------------------------------------------
// Persistent recurrence, ONE launch for T=512 steps. 256 blocks, block owns
// 4 H-columns for all 32 batches; W rows LDS-resident.
//
// Sync design (the round-3 lesson): NEVER trigger buffer_wbl2 (agent-release
// fence = full per-XCD L2 writeback on gfx950). Instead:
//   - z results stored with RELAXED agent-scope atomic stores (sc1: bypass
//     L2, land at the coherence point) -> no dirty z lines in L2.
//   - s_waitcnt(0) drains them, then RELAXED agent fetch_add to arrive.
//   - spin on RELAXED agent loads (no per-poll buffer_inv) + s_sleep backoff.
//   - ONE acquire fence (buffer_inv, invalidate-only) per block per step so
//     h/pre reads re-fetch fresh (G16).
// ---------------------------------------------------------------------------
__global__ __launch_bounds__(256)
void rnn_persistent(float* __restrict__ z, const float* __restrict__ h0,
                    const float* __restrict__ Whh, const float* __restrict__ bhh,
                    unsigned int* __restrict__ ctr) {
  __shared__ float Ws[4][1032];      // 4 W_hh rows, resident for whole kernel
  __shared__ float hs[32][132];      // h tile: 32 b x 128 k (+pad)
  __shared__ float red[8 * 32 * 4];  // k-split partials

  const int tid = threadIdx.x;
  const int j0 = blockIdx.x * 4;

  // ---- stage W rows once ----
  {
    const int j  = tid >> 6;
    const int c4 = tid & 63;
    const float4* src = (const float4*)(Whh + (size_t)(j0 + j) * H_);
#pragma unroll
    for (int i = 0; i < 4; ++i) {
      float4 v = src[c4 + 64 * i];
      *(float4*)&Ws[j][(c4 + 64 * i) * 4] = v;
    }
  }

  const int b    = tid & 31;
  const int s    = tid >> 5;       // 0..7 k-split
  const int srow = tid >> 3;       // staging row 0..31
  const int sc4  = tid & 7;

  for (int t = 0; t < T_; ++t) {
    const float* hbase;
    size_t hstride;
    if (t == 0) { hbase = h0;                     hstride = H_; }
    else        { hbase = z + (size_t)(t-1) * H_; hstride = (size_t)T_ * H_; }

    float partial[4] = {0.f, 0.f, 0.f, 0.f};

    for (int kt = 0; kt < H_; kt += 128) {
      __syncthreads();
      const float* hsrc = hbase + (size_t)srow * hstride + kt;
#pragma unroll
      for (int i = 0; i < 4; ++i) {
        float4 v = *(const float4*)(hsrc + (sc4 + 8 * i) * 4);
        *(float4*)&hs[srow][(sc4 + 8 * i) * 4] = v;
      }
      __syncthreads();
#pragma unroll
      for (int m = 0; m < 4; ++m) {
        const int g  = m * 8 + s;
        float4 hv = *(const float4*)&hs[b][g * 4];
        const int kw = kt + g * 4;
#pragma unroll
        for (int j = 0; j < 4; ++j) {
          float4 wv = *(const float4*)&Ws[j][kw];
          partial[j] += hv.x*wv.x + hv.y*wv.y + hv.z*wv.z + hv.w*wv.w;
        }
      }
    }

    __syncthreads();
#pragma unroll
    for (int j = 0; j < 4; ++j) red[(s * 32 + b) * 4 + j] = partial[j];
    __syncthreads();

    if (tid < 128) {
      const int rb = tid >> 2;
      const int rj = tid & 3;
      float v = 0.f;
#pragma unroll
      for (int ss = 0; ss < 8; ++ss) v += red[(ss * 32 + rb) * 4 + rj];
      const size_t idx = (size_t)rb * T_ * H_ + (size_t)t * H_ + j0 + rj;
      v += z[idx] + bhh[j0 + rj];
      // sc1 store: bypasses L2, lands at coherence point -> no wbl2 needed.
      __hip_atomic_store(&z[idx], tanhf(v), __ATOMIC_RELAXED,
                         __HIP_MEMORY_SCOPE_AGENT);
    }

    // drain this wave's sc1 stores to the coherence point
    __builtin_amdgcn_s_waitcnt(0);
    __syncthreads();   // all waves drained

    if (tid == 0) {
      // relaxed arrive: ordered behind drained stores at the coherence point
      __hip_atomic_fetch_add(ctr, 1u, __ATOMIC_RELAXED,
                             __HIP_MEMORY_SCOPE_AGENT);
      const unsigned target = (unsigned)(t + 1) * NBLK;
      while (__hip_atomic_load(ctr, __ATOMIC_RELAXED,
                               __HIP_MEMORY_SCOPE_AGENT) < target)
        __builtin_amdgcn_s_sleep(4);
    }
    __syncthreads();
    // acquire: buffer_inv (invalidate-only) so peers' z writes are re-fetched
    __builtin_amdgcn_fence(__ATOMIC_ACQUIRE, "agent");
  }
}

// ---------------------------------------------------------------------------
// Row softmax in place over O_=512 columns. One wave per row.
// ---------------------------------------------------------------------------
__global__ __launch_bounds__(256)
void softmax_rows(float* __restrict__ P) {
  const int row  = blockIdx.x * 4 + (threadIdx.x >> 6);
  const int lane = threadIdx.x & 63;
  float* p = P + (size_t)row * O_;
  float4 v0 = *(const float4*)(p + lane * 4);
  float4 v1 = *(const float4*)(p + 256 + lane * 4);

  float m = fmaxf(fmaxf(fmaxf(v0.x, v0.y), fmaxf(v0.z, v0.w)),
                  fmaxf(fmaxf(v1.x, v1.y), fmaxf(v1.z, v1.w)));
#pragma unroll
  for (int off = 32; off; off >>= 1) m = fmaxf(m, __shfl_xor(m, off, 64));

  v0.x = __expf(v0.x - m); v0.y = __expf(v0.y - m);
  v0.z = __expf(v0.z - m); v0.w = __expf(v0.w - m);
  v1.x = __expf(v1.x - m); v1.y = __expf(v1.y - m);
  v1.z = __expf(v1.z - m); v1.w = __expf(v1.w - m);

  float s = v0.x + v0.y + v0.z + v0.w + v1.x + v1.y + v1.z + v1.w;
#pragma unroll
  for (int off = 32; off; off >>= 1) s += __shfl_xor(s, off, 64);
  const float inv = 1.f / s;

  v0.x *= inv; v0.y *= inv; v0.z *= inv; v0.w *= inv;
  v1.x *= inv; v1.y *= inv; v1.z *= inv; v1.w *= inv;
  *(float4*)(p + lane * 4)       = v0;
  *(float4*)(p + 256 + lane * 4) = v1;
}

// ---------------------------------------------------------------------------
extern "C" void kernel_launch(void* const* d_in, const int* in_sizes, int n_in,
                              void* d_out, int out_size, void* d_ws, size_t ws_size,
                              hipStream_t stream) {
  const float* x    = (const float*)d_in[0];   // [B,T,I]
  const float* h0   = (const float*)d_in[1];   // [1,B,H]
  const float* Wih  = (const float*)d_in[2];   // [H,I]
  const float* Whh  = (const float*)d_in[3];   // [H,H]
  const float* bih  = (const float*)d_in[4];   // [H]
  const float* bhh  = (const float*)d_in[5];   // [H]
  const float* Wout = (const float*)d_in[6];   // [O,H]
  const float* bout = (const float*)d_in[7];   // [O]

  float* outp = (float*)d_out;                       // [B,T,O]
  float* z    = (float*)d_out + (size_t)MT * O_;     // [B,T,H]
  unsigned int* ctr = (unsigned int*)d_ws;           // barrier counter

  // zero the barrier counter (ws is poisoned 0xAA before every replay)
  (void)hipMemsetAsync(ctr, 0, 64, stream);

  // Phase 1: pre = x @ W_ih^T + b_ih, written directly into z region
  gemm_nt_bias<<<dim3(MT / 128, H_ / 128), 256, 0, stream>>>(z, x, Wih, bih, MT, H_, I_);

  // Phase 2: ONE persistent kernel for all 512 recurrence steps
  rnn_persistent<<<dim3(NBLK), 256, 0, stream>>>(z, h0, Whh, bhh, ctr);

  // Phase 3: logits = z @ W_out^T + b_out, then row softmax in place
  gemm_nt_bias<<<dim3(MT / 128, O_ / 128), 256, 0, stream>>>(outp, z, Wout, bout, MT, O_, H_);
  softmax_rows<<<dim3(MT / 4), 256, 0, stream>>>(outp);
}

// Round 5
// 6345.947 us; speedup vs baseline: 3.7822x; 1.4546x over previous
//
#include <hip/hip_runtime.h>
#include <math.h>

#define B_ 32
#define T_ 512
#define I_ 512
#define H_ 1024
#define O_ 512
#define MT (B_*T_)   // 16384 rows
#define NBLK 256     // 8 groups x 32 blocks
#define NGRP 8
#define GSZ  32

// ---------------------------------------------------------------------------
// GEMM: C[m][n] = bias[n] + sum_k A[m][k] * Bm[n][k]   (both row-major, "NT")
// ---------------------------------------------------------------------------
__global__ __launch_bounds__(256)
void gemm_nt_bias(float* __restrict__ C, const float* __restrict__ A,
                  const float* __restrict__ Bm, const float* __restrict__ bias,
                  int M, int N, int K) {
  __shared__ float As[16][132];
  __shared__ float Bs[16][132];
  const int tid = threadIdx.x;
  const int bm = blockIdx.x * 128;
  const int bn = blockIdx.y * 128;
  const int lr = tid >> 2;
  const int lc = (tid & 3) * 4;
  const int tm = (tid >> 4) * 8;
  const int tn = (tid & 15) * 8;

  float acc[8][8];
#pragma unroll
  for (int i = 0; i < 8; ++i)
#pragma unroll
    for (int j = 0; j < 8; ++j) acc[i][j] = 0.f;

  for (int k0 = 0; k0 < K; k0 += 16) {
    float4 a0 = *(const float4*)(A  + (size_t)(bm + lr)      * K + k0 + lc);
    float4 a1 = *(const float4*)(A  + (size_t)(bm + lr + 64) * K + k0 + lc);
    float4 b0 = *(const float4*)(Bm + (size_t)(bn + lr)      * K + k0 + lc);
    float4 b1 = *(const float4*)(Bm + (size_t)(bn + lr + 64) * K + k0 + lc);
    __syncthreads();
    As[lc+0][lr]    = a0.x; As[lc+1][lr]    = a0.y; As[lc+2][lr]    = a0.z; As[lc+3][lr]    = a0.w;
    As[lc+0][lr+64] = a1.x; As[lc+1][lr+64] = a1.y; As[lc+2][lr+64] = a1.z; As[lc+3][lr+64] = a1.w;
    Bs[lc+0][lr]    = b0.x; Bs[lc+1][lr]    = b0.y; Bs[lc+2][lr]    = b0.z; Bs[lc+3][lr]    = b0.w;
    Bs[lc+0][lr+64] = b1.x; Bs[lc+1][lr+64] = b1.y; Bs[lc+2][lr+64] = b1.z; Bs[lc+3][lr+64] = b1.w;
    __syncthreads();
#pragma unroll
    for (int k = 0; k < 16; ++k) {
      float a[8], b[8];
      *(float4*)&a[0] = *(const float4*)&As[k][tm];
      *(float4*)&a[4] = *(const float4*)&As[k][tm + 4];
      *(float4*)&b[0] = *(const float4*)&Bs[k][tn];
      *(float4*)&b[4] = *(const float4*)&Bs[k][tn + 4];
#pragma unroll
      for (int i = 0; i < 8; ++i)
#pragma unroll
        for (int j = 0; j < 8; ++j) acc[i][j] += a[i] * b[j];
    }
  }

  float bv[8];
#pragma unroll
  for (int j = 0; j < 8; ++j) bv[j] = bias[bn + tn + j];
#pragma unroll
  for (int i = 0; i < 8; ++i) {
    float* crow = C + (size_t)(bm + tm + i) * N + bn + tn;
    float4 o0 = {acc[i][0]+bv[0], acc[i][1]+bv[1], acc[i][2]+bv[2], acc[i][3]+bv[3]};
    float4 o1 = {acc[i][4]+bv[4], acc[i][5]+bv[5], acc[i][6]+bv[6], acc[i][7]+bv[7]};
    *(float4*)(crow)     = o0;
    *(float4*)(crow + 4) = o1;
  }
}

// ---------------------------------------------------------------------------
// Persistent recurrence, group-local chains.
// 8 groups x 32 blocks. Group g owns batches 4g..4g+3. Block (rank in group)
// owns 32 j-columns for those 4 batches. W_hh slice lives in REGISTERS
// (128 VGPR/thread, loaded once) -> no W traffic ever, immune to buffer_inv.
// Per step: one-burst 16KB h stage -> reg-tile dot (4j x 4b x 32k /thread,
// 32-way k-split) -> LDS reduce -> tanh -> sc1 store -> 32-wide group barrier.
// Sync recipe = round-4-validated: relaxed sc1 stores + waitcnt drain +
// relaxed arrive + spin + acquire(buffer_inv). No wbl2 anywhere.
// ---------------------------------------------------------------------------
__global__ __launch_bounds__(256, 1)
void rnn_persistent(float* __restrict__ z, const float* __restrict__ h0,
                    const float* __restrict__ Whh, const float* __restrict__ bhh,
                    unsigned int* __restrict__ ctrs) {
  __shared__ float hs[4][1032];     // h tile: 4 batches x 1024 (+8 pad)
  __shared__ float red[128][33];    // 128 outputs x 32 k-split partials (+1 pad)
  __shared__ float zout[4][33];     // store-coalescing bounce

  const int tid  = threadIdx.x;
  const int g    = blockIdx.x & 7;        // group
  const int rank = blockIdx.x >> 3;       // 0..31 within group
  const int bbase = g * 4;                // first batch of group
  const int j0    = rank * 32;            // first j-column of block
  unsigned int* ctr = ctrs + g * 64;      // 256-B spaced counters

  const int s  = tid & 31;                // 32-way k-split lane
  const int jg = tid >> 5;                // j-group 0..7

  // ---- W_hh slice into registers (once): w[jj][m] = W[j0+jg*4+jj][(m*32+s)*4 ..+3]
  float4 w[4][8];
#pragma unroll
  for (int jj = 0; jj < 4; ++jj) {
    const float* wr = Whh + (size_t)(j0 + jg * 4 + jj) * H_;
#pragma unroll
    for (int m = 0; m < 8; ++m)
      w[jj][m] = *(const float4*)(wr + (m * 32 + s) * 4);
  }

  // reducer-lane constants (tid<128): output = (j_local=tid>>2, bb=tid&3)
  const int rj = tid >> 2;
  const int rb = tid & 3;
  float bhh_r = 0.f;
  if (tid < 128) bhh_r = bhh[j0 + rj];

  const int sbb = tid >> 6;               // staging batch 0..3
  const int skk = tid & 63;               // staging k4 base

  for (int t = 0; t < T_; ++t) {
    // prefetch pre (GEMM output at z[.][t][.]; only this block writes it, later)
    float pre_r = 0.f;
    if (tid < 128)
      pre_r = z[(size_t)(bbase + rb) * T_ * H_ + (size_t)t * H_ + j0 + rj];

    // ---- stage h_{t-1}: 16KB in one burst (4 coalesced float4 loads/thread)
    {
      const float* hr = (t == 0)
        ? (h0 + (size_t)(bbase + sbb) * H_)
        : (z + (size_t)(bbase + sbb) * T_ * H_ + (size_t)(t - 1) * H_);
#pragma unroll
      for (int it = 0; it < 4; ++it) {
        const int k4 = skk + 64 * it;
        float4 v = *(const float4*)(hr + k4 * 4);
        *(float4*)&hs[sbb][k4 * 4] = v;
      }
    }
    __syncthreads();

    // ---- reg-tile dot: acc[jj][bb] over this thread's 32 k's
    float acc[4][4];
#pragma unroll
    for (int jj = 0; jj < 4; ++jj)
#pragma unroll
      for (int bb = 0; bb < 4; ++bb) acc[jj][bb] = 0.f;

#pragma unroll
    for (int m = 0; m < 8; ++m) {
      float4 hv[4];
#pragma unroll
      for (int bb = 0; bb < 4; ++bb)
        hv[bb] = *(const float4*)&hs[bb][(m * 32 + s) * 4];
#pragma unroll
      for (int jj = 0; jj < 4; ++jj)
#pragma unroll
        for (int bb = 0; bb < 4; ++bb)
          acc[jj][bb] += w[jj][m].x * hv[bb].x + w[jj][m].y * hv[bb].y
                       + w[jj][m].z * hv[bb].z + w[jj][m].w * hv[bb].w;
    }

    // ---- k-split partials to LDS
#pragma unroll
    for (int jj = 0; jj < 4; ++jj)
#pragma unroll
      for (int bb = 0; bb < 4; ++bb)
        red[(jg * 4 + jj) * 4 + bb][s] = acc[jj][bb];
    __syncthreads();

    // ---- reduce + bias + pre + tanh
    if (tid < 128) {
      float v = 0.f;
#pragma unroll
      for (int ss = 0; ss < 32; ++ss) v += red[tid][ss];
      v += pre_r + bhh_r;
      zout[rb][rj] = tanhf(v);
    }
    __syncthreads();

    // ---- coalesced sc1 store (32-consecutive floats per batch row)
    if (tid < 128) {
      const int sb = tid >> 5, sj = tid & 31;
      __hip_atomic_store(
          &z[(size_t)(bbase + sb) * T_ * H_ + (size_t)t * H_ + j0 + sj],
          zout[sb][sj], __ATOMIC_RELAXED, __HIP_MEMORY_SCOPE_AGENT);
    }

    // ---- group barrier (32-wide)
    __builtin_amdgcn_s_waitcnt(0);   // drain sc1 stores to coherence point
    __syncthreads();
    if (tid == 0) {
      __hip_atomic_fetch_add(ctr, 1u, __ATOMIC_RELAXED, __HIP_MEMORY_SCOPE_AGENT);
      const unsigned target = (unsigned)(t + 1) * GSZ;
      while (__hip_atomic_load(ctr, __ATOMIC_RELAXED, __HIP_MEMORY_SCOPE_AGENT) < target)
        __builtin_amdgcn_s_sleep(1);
    }
    __syncthreads();
    __builtin_amdgcn_fence(__ATOMIC_ACQUIRE, "agent");  // invalidate-only
  }
}

// ---------------------------------------------------------------------------
// Row softmax in place over O_=512 columns. One wave per row.
// ---------------------------------------------------------------------------
__global__ __launch_bounds__(256)
void softmax_rows(float* __restrict__ P) {
  const int row  = blockIdx.x * 4 + (threadIdx.x >> 6);
  const int lane = threadIdx.x & 63;
  float* p = P + (size_t)row * O_;
  float4 v0 = *(const float4*)(p + lane * 4);
  float4 v1 = *(const float4*)(p + 256 + lane * 4);

  float m = fmaxf(fmaxf(fmaxf(v0.x, v0.y), fmaxf(v0.z, v0.w)),
                  fmaxf(fmaxf(v1.x, v1.y), fmaxf(v1.z, v1.w)));
#pragma unroll
  for (int off = 32; off; off >>= 1) m = fmaxf(m, __shfl_xor(m, off, 64));

  v0.x = __expf(v0.x - m); v0.y = __expf(v0.y - m);
  v0.z = __expf(v0.z - m); v0.w = __expf(v0.w - m);
  v1.x = __expf(v1.x - m); v1.y = __expf(v1.y - m);
  v1.z = __expf(v1.z - m); v1.w = __expf(v1.w - m);

  float s = v0.x + v0.y + v0.z + v0.w + v1.x + v1.y + v1.z + v1.w;
#pragma unroll
  for (int off = 32; off; off >>= 1) s += __shfl_xor(s, off, 64);
  const float inv = 1.f / s;

  v0.x *= inv; v0.y *= inv; v0.z *= inv; v0.w *= inv;
  v1.x *= inv; v1.y *= inv; v1.z *= inv; v1.w *= inv;
  *(float4*)(p + lane * 4)       = v0;
  *(float4*)(p + 256 + lane * 4) = v1;
}

// ---------------------------------------------------------------------------
extern "C" void kernel_launch(void* const* d_in, const int* in_sizes, int n_in,
                              void* d_out, int out_size, void* d_ws, size_t ws_size,
                              hipStream_t stream) {
  const float* x    = (const float*)d_in[0];   // [B,T,I]
  const float* h0   = (const float*)d_in[1];   // [1,B,H]
  const float* Wih  = (const float*)d_in[2];   // [H,I]
  const float* Whh  = (const float*)d_in[3];   // [H,H]
  const float* bih  = (const float*)d_in[4];   // [H]
  const float* bhh  = (const float*)d_in[5];   // [H]
  const float* Wout = (const float*)d_in[6];   // [O,H]
  const float* bout = (const float*)d_in[7];   // [O]

  float* outp = (float*)d_out;                       // [B,T,O]
  float* z    = (float*)d_out + (size_t)MT * O_;     // [B,T,H]
  unsigned int* ctrs = (unsigned int*)d_ws;          // 8 group counters, 256-B spaced

  (void)hipMemsetAsync(ctrs, 0, NGRP * 256, stream);

  // Phase 1: pre = x @ W_ih^T + b_ih, written directly into z region
  gemm_nt_bias<<<dim3(MT / 128, H_ / 128), 256, 0, stream>>>(z, x, Wih, bih, MT, H_, I_);

  // Phase 2: ONE persistent kernel, group-local barriers
  rnn_persistent<<<dim3(NBLK), 256, 0, stream>>>(z, h0, Whh, bhh, ctrs);

  // Phase 3: logits = z @ W_out^T + b_out, then row softmax in place
  gemm_nt_bias<<<dim3(MT / 128, O_ / 128), 256, 0, stream>>>(outp, z, Wout, bout, MT, O_, H_);
  softmax_rows<<<dim3(MT / 4), 256, 0, stream>>>(outp);
}